// Round 19
// baseline (47.145 us; speedup 1.0000x reference)
//
#include <hip/hip_runtime.h>
#include <math.h>

#define NC 2048            // 2H + 2W (H = W = 512)
#define NB 4
#define NS 4096
#define INV_TEMP (1.0f / 256.0f)
#define LOG2E 1.44269504088896340736f
#define CL 16              // chunk length (rows per loss block)
#define NCH (NS / CL)      // 256 chunks per batch
#define P1_NG 16           // scan groups per P1 block (512 thr / 32 ch)
#define P1_GS (NS / P1_NG) // 256 s per group
#define P1_GC (P1_GS / CL) // 16 chunks per group
#define LOSS_NBLK (NB * NCH)   // 1024 loss blocks

typedef float f32x4 __attribute__((ext_vector_type(4)));
typedef float f32x2 __attribute__((ext_vector_type(2)));

// 64-lane wave sum on the VALU pipe (DPP), no DS-pipe traffic. (R16.)
#define WAVE_SUM_DPP(x)                                                       \
    asm volatile("s_nop 1\n\t"                                                \
                 "v_add_f32 %0, %0, %0 row_shr:1 bound_ctrl:0" : "+v"(x));    \
    asm volatile("s_nop 1\n\t"                                                \
                 "v_add_f32 %0, %0, %0 row_shr:2 bound_ctrl:0" : "+v"(x));    \
    asm volatile("s_nop 1\n\t"                                                \
                 "v_add_f32 %0, %0, %0 row_shr:4 bound_ctrl:0" : "+v"(x));    \
    asm volatile("s_nop 1\n\t"                                                \
                 "v_add_f32 %0, %0, %0 row_shr:8 bound_ctrl:0" : "+v"(x));    \
    asm volatile("s_nop 1\n\t"                                                \
                 "v_add_f32 %0, %0, %0 row_bcast:15 row_mask:0xa" : "+v"(x)); \
    asm volatile("s_nop 1\n\t"                                                \
                 "v_add_f32 %0, %0, %0 row_bcast:31 row_mask:0xc" : "+v"(x));

__device__ __forceinline__ float wave_total(float x)
{
    return __uint_as_float(__builtin_amdgcn_readlane(__float_as_uint(x), 63));
}

// ---------------------------------------------------------------------------
// Phase 1: per-(b, 32-channel tile) block.  (R16 verbatim.)
// ---------------------------------------------------------------------------
__global__ __launch_bounds__(512) void tdl_scan_kernel(
    const float* __restrict__ target, float* __restrict__ rstart)
{
    const int b     = blockIdx.x >> 6;   // 64 channel-tiles per batch
    const int ctile = blockIdx.x & 63;
    const int tid = threadIdx.x;
    const int ci  = tid & 31;            // channel within tile
    const int g   = tid >> 5;            // scan group (0..15)

    __shared__ float shbuf[NS * 4];      // 64 KB: f32x4 ev[NS] then f32x2 pk[NS]
    __shared__ float shL[P1_NG][32];
    __shared__ float shG[P1_NG];
    f32x4* ev = (f32x4*)shbuf;
    f32x2* pk = (f32x2*)shbuf;

    const int  seg    = ctile >> 4;                       // 0..3
    const bool useH   = (seg < 2);
    const float segPar = (float)(seg & 1);
    const float crel  = (float)(((ctile & 15) << 5) + ci); // in-segment channel

    const float* tb = target + (size_t)b * NS * 4;

#pragma unroll
    for (int m = 0; m < 8; ++m) {
        int s = m * 512 + tid;
        ev[s] = *((const f32x4*)tb + s);
    }
    __syncthreads();

    float dec_r[8], enc_r[8];
#pragma unroll
    for (int m = 0; m < 8; ++m) {
        int s = m * 512 + tid;
        f32x4 e = ev[s];
        dec_r[m] = (s == NS - 1) ? 0.0f
                  : __expf(-(ev[s + 1].x - e.x) * INV_TEMP);
        enc_r[m] = (e.w == segPar) ? (useH ? e.y : e.z) : -1.0f;
    }
    float alp[P1_GC];
    {
        const int gs = g * P1_GS;
#pragma unroll
        for (int q = 0; q < P1_GC; ++q) {
            int se = gs + q * CL;
            alp[q] = (g == P1_NG - 1 && q == P1_GC - 1) ? 0.0f
                     : __expf(-(ev[se + CL].x - ev[se].x) * INV_TEMP);
        }
        if (ci == 0) {
            shG[g] = (g == P1_NG - 1) ? 0.0f
                     : __expf(-(ev[gs + P1_GS].x - ev[gs].x) * INV_TEMP);
        }
    }
    __syncthreads();

#pragma unroll
    for (int m = 0; m < 8; ++m) {
        int s = m * 512 + tid;
        f32x2 v; v.x = dec_r[m]; v.y = enc_r[m];
        pk[s] = v;
    }
    __syncthreads();

    float cs[P1_GC];
    {
        const int gs = g * P1_GS;
#pragma unroll
        for (int q = P1_GC - 1; q >= 0; --q) {
            float v = 0.0f;
            const int base = gs + q * CL;
#pragma unroll
            for (int i = CL - 1; i >= 0; --i) {
                f32x2 e = pk[base + i];
                v = fmaf(v, e.x, (e.y == crel) ? 1.0f : 0.0f);
            }
            cs[q] = v;
        }
    }

    float L = 0.0f;
#pragma unroll
    for (int q = P1_GC - 1; q >= 0; --q) L = fmaf(alp[q], L, cs[q]);
    shL[g][ci] = L;
    __syncthreads();

    float X = 0.0f;
#pragma unroll
    for (int j = P1_NG - 1; j >= 1; --j)
        if (j > g) X = fmaf(shG[j], X, shL[j][ci]);

    float* rs = rstart + ((size_t)b * NCH + g * P1_GC) * NC + (ctile * 32 + ci);
    float carry = X;
#pragma unroll
    for (int q = P1_GC - 1; q >= 0; --q) {
        carry = fmaf(alp[q], carry, cs[q]);
        rs[(size_t)q * NC] = carry;
    }
}

// ---------------------------------------------------------------------------
// Phase 2: fused scan + soft-CE loss.  (R16 verbatim — best config 31.0 µs.)
// PROBE NOTE: launched TWICE this round to measure its isolated cost
// (deterministic: re-reads unchanged rstart, rewrites identical partials).
// ---------------------------------------------------------------------------
__global__ __launch_bounds__(256) void tdl_loss_kernel(
    const float* __restrict__ pred, const float* __restrict__ target,
    const float* __restrict__ rstart, float* __restrict__ partials)
{
    const int blk = blockIdx.x;
    const int b = blk >> 8;              // / NCH
    const int k = blk & (NCH - 1);
    const int s0 = k * CL;
    const int tid = threadIdx.x;
    const int wv  = (tid >> 6) & 1;      // 0: H-pair, 1: W-pair
    const int rh  = tid >> 7;            // 0: rows 15..8, 1: rows 7..0
    const int ln  = tid & 63;

    __shared__ f32x4 ev[CL];             // {dec, p, h, w}
    __shared__ float sh4[4];

    if (tid < CL) {
        const float* tg = target + ((size_t)b * NS + s0 + tid) * 4;
        float t0 = tg[0];
        int s = s0 + tid;
        float dec = (s == NS - 1 || s == 0) ? 0.0f
                   : __expf(-(tg[4] - t0) * INV_TEMP);   // tg[4] = t[s+1]
        f32x4 e; e.x = dec; e.y = tg[3]; e.z = tg[1]; e.w = tg[2];
        ev[tid] = e;
    }
    __syncthreads();

    const int lc   = ln * 4;             // lane offset within a 256-ch quarter
    const int segA = wv * 2;             // even segment of my pair
    const size_t pbase = (size_t)b * NS * NC;

    float vA[8], vB[8];
    if (k == NCH - 1) {
#pragma unroll
        for (int j = 0; j < 8; ++j) { vA[j] = 0.0f; vB[j] = 0.0f; }
    } else {
        const float* rrow = rstart + ((size_t)b * NCH + k + 1) * NC;
#pragma unroll
        for (int q = 0; q < 2; ++q) {
            f32x4 ra = *(const f32x4*)(rrow + segA * 512 + q * 256 + lc);
            f32x4 rb = *(const f32x4*)(rrow + (segA + 1) * 512 + q * 256 + lc);
#pragma unroll
            for (int j = 0; j < 4; ++j) {
                vA[q*4+j] = ra[j] * LOG2E;
                vB[q*4+j] = rb[j] * LOG2E;
            }
        }
    }

    if (rh) {
#pragma unroll
        for (int i = CL - 1; i >= CL / 2; --i) {
            f32x4 e = ev[i];
            const float d    = e.x;
            const float pv   = e.y;
            const float idxf = wv ? e.w : e.z;
            const float aA = (1.0f - pv) * LOG2E;
            const float aB = pv * LOG2E;
#pragma unroll
            for (int q = 0; q < 2; ++q) {
#pragma unroll
                for (int j = 0; j < 4; ++j) {
                    const int id = q * 4 + j;
                    const float myc = (float)(q * 256 + lc + j);
                    const bool m = (idxf == myc);
                    vA[id] = fmaf(vA[id], d, m ? aA : 0.0f);
                    vB[id] = fmaf(vB[id], d, m ? aB : 0.0f);
                }
            }
        }
    }

    const int itop = rh ? (CL / 2 - 1) : (CL - 1);  // 7 or 15

    f32x4 pf0[2], pf1[2];
    {
        const int paT = (int)ev[itop].y;
        const float* pr = pred + pbase + (size_t)(s0 + itop) * NC
                          + (segA + paT) * 512 + lc;
        pf0[0] = *(const f32x4*)pr; pf0[1] = *(const f32x4*)(pr + 256);
        const int paU = (int)ev[itop - 1].y;
        const float* pr2 = pred + pbase + (size_t)(s0 + itop - 1) * NC
                           + (segA + paU) * 512 + lc;
        pf1[0] = *(const f32x4*)pr2; pf1[1] = *(const f32x4*)(pr2 + 256);
    }

    float acc = 0.0f;
#pragma unroll
    for (int r = 0; r < 8; ++r) {
        const int i = itop - r;
        f32x4 cur0 = pf0[0], cur1 = pf0[1];
        pf0[0] = pf1[0]; pf0[1] = pf1[1];
        if (r < 6) {
            const int pa = (int)ev[i - 2].y;
            const float* pr = pred + pbase + (size_t)(s0 + i - 2) * NC
                              + (segA + pa) * 512 + lc;
            pf1[0] = *(const f32x4*)pr; pf1[1] = *(const f32x4*)(pr + 256);
        }

        f32x4 e = ev[i];
        const float d    = e.x;
        const float pv   = e.y;                    // 0.0 or 1.0 exactly
        const float idxf = wv ? e.w : e.z;
        const float aA = (1.0f - pv) * LOG2E;
        const float aB = pv * LOG2E;

        float ser = 0.0f, dot = 0.0f, sep = 0.0f;
#pragma unroll
        for (int q = 0; q < 2; ++q) {
            const f32x4 cq = q ? cur1 : cur0;
#pragma unroll
            for (int j = 0; j < 4; ++j) {
                const int id = q * 4 + j;
                const float myc = (float)(q * 256 + lc + j);
                const bool m = (idxf == myc);
                vA[id] = fmaf(vA[id], d, m ? aA : 0.0f);
                vB[id] = fmaf(vB[id], d, m ? aB : 0.0f);
                const float vs = (pv != 0.0f) ? vB[id] : vA[id];
                const float ex = exp2f(vs);
                const float pj = cq[j];
                ser += ex;
                dot = fmaf(ex, pj, dot);
                sep += __expf(pj);
            }
        }

        WAVE_SUM_DPP(ser)
        WAVE_SUM_DPP(dot)
        WAVE_SUM_DPP(sep)
        const float serT = wave_total(ser);
        const float dotT = wave_total(dot);
        const float sepT = wave_total(sep);
        acc += __logf(sepT) - dotT * __builtin_amdgcn_rcpf(serT);
    }

    if (ln == 0) sh4[tid >> 6] = acc;
    __syncthreads();
    if (tid == 0) partials[blk] = sh4[0] + sh4[1] + sh4[2] + sh4[3];
}

// ---------------------------------------------------------------------------
// Phase 3: tiny reduce — 1 block, 256 threads, 4 KB of partials -> out[0].
// ---------------------------------------------------------------------------
__global__ __launch_bounds__(256) void tdl_reduce_kernel(
    const float* __restrict__ partials, float* __restrict__ out)
{
    const int tid = threadIdx.x;
    __shared__ float sh4[4];

    float s = 0.0f;
#pragma unroll
    for (int i = 0; i < LOSS_NBLK / 256; ++i)
        s += partials[i * 256 + tid];
#pragma unroll
    for (int off = 32; off > 0; off >>= 1)
        s += __shfl_xor(s, off, 64);
    if ((tid & 63) == 0) sh4[tid >> 6] = s;
    __syncthreads();
    if (tid == 0)
        out[0] = (sh4[0] + sh4[1] + sh4[2] + sh4[3])
                 * (1.0f / ((float)NB * (float)NS));
}

// ---------------------------------------------------------------------------
extern "C" void kernel_launch(void* const* d_in, const int* in_sizes, int n_in,
                              void* d_out, int out_size, void* d_ws, size_t ws_size,
                              hipStream_t stream)
{
    const float* pred   = (const float*)d_in[0];
    const float* target = (const float*)d_in[1];
    float* out    = (float*)d_out;
    float* rstart = (float*)d_ws;                       // 8 MiB
    float* partials = rstart + (size_t)NB * NCH * NC;   // 4 KiB

    tdl_scan_kernel<<<NB * 64, 512, 0, stream>>>(target, rstart);
    // PROBE: duplicated loss dispatch — T_total - 31.0 isolates its cost.
    tdl_loss_kernel<<<NB * NCH, 256, 0, stream>>>(pred, target, rstart, partials);
    tdl_loss_kernel<<<NB * NCH, 256, 0, stream>>>(pred, target, rstart, partials);
    tdl_reduce_kernel<<<1, 256, 0, stream>>>(partials, out);
}

// Round 20
// 32.194 us; speedup vs baseline: 1.4644x; 1.4644x over previous
//
#include <hip/hip_runtime.h>
#include <math.h>

#define NC 2048            // 2H + 2W (H = W = 512)
#define NB 4
#define NS 4096
#define INV_TEMP (1.0f / 256.0f)
#define LOG2E 1.44269504088896340736f
#define CL 16              // chunk length (rows per loss block)
#define NCH (NS / CL)      // 256 chunks per batch
#define P2_NG 32           // scan groups per scan block (512 thr / 16 ch)
#define P2_GS (NS / P2_NG) // 128 s per group
#define P2_GC (P2_GS / CL) // 8 chunks per group
#define LOSS_NBLK (NB * NCH)   // 1024 loss blocks

typedef float f32x4 __attribute__((ext_vector_type(4)));
typedef float f32x2 __attribute__((ext_vector_type(2)));

// 64-lane wave sum on the VALU pipe (DPP), no DS-pipe traffic. (R16.)
#define WAVE_SUM_DPP(x)                                                       \
    asm volatile("s_nop 1\n\t"                                                \
                 "v_add_f32 %0, %0, %0 row_shr:1 bound_ctrl:0" : "+v"(x));    \
    asm volatile("s_nop 1\n\t"                                                \
                 "v_add_f32 %0, %0, %0 row_shr:2 bound_ctrl:0" : "+v"(x));    \
    asm volatile("s_nop 1\n\t"                                                \
                 "v_add_f32 %0, %0, %0 row_shr:4 bound_ctrl:0" : "+v"(x));    \
    asm volatile("s_nop 1\n\t"                                                \
                 "v_add_f32 %0, %0, %0 row_shr:8 bound_ctrl:0" : "+v"(x));    \
    asm volatile("s_nop 1\n\t"                                                \
                 "v_add_f32 %0, %0, %0 row_bcast:15 row_mask:0xa" : "+v"(x)); \
    asm volatile("s_nop 1\n\t"                                                \
                 "v_add_f32 %0, %0, %0 row_bcast:31 row_mask:0xc" : "+v"(x));

__device__ __forceinline__ float wave_total(float x)
{
    return __uint_as_float(__builtin_amdgcn_readlane(__float_as_uint(x), 63));
}

// ---------------------------------------------------------------------------
// Phase 1 v2: per-(b, 16-channel tile) block — 512 blocks (2/CU, was 1/CU).
//  * LDS holds only t (16 KB) + pk stream (32 KB, separate region -> one
//    fewer barrier); h/w/p never touch LDS (enc computed from the staging
//    thread's own registers).
//  * 32 groups x 8 chunks: phase-4 serial work per thread halved (128 iters).
// ---------------------------------------------------------------------------
__global__ __launch_bounds__(512) void tdl_scan_kernel(
    const float* __restrict__ target, float* __restrict__ rstart)
{
    const int b     = blockIdx.x >> 7;   // 128 channel-tiles per batch
    const int ctile = blockIdx.x & 127;
    const int tid = threadIdx.x;
    const int ci  = tid & 15;            // channel within tile
    const int g   = tid >> 4;            // scan group (0..31)

    __shared__ float st[NS];             // 16 KB: t only
    __shared__ f32x2 pk[NS];             // 32 KB: {dec, enc}
    __shared__ float shL[P2_NG][16];
    __shared__ float shG[P2_NG];

    const int  seg    = ctile >> 5;                       // 0..3
    const bool useH   = (seg < 2);
    const float segPar = (float)(seg & 1);
    const float crel  = (float)(((ctile & 31) << 4) + ci); // in-segment channel

    const float* tb = target + (size_t)b * NS * 4;

    // 1. stage: t -> LDS; h/w/p stay in registers (enc computed locally)
    float enc_r[8];
#pragma unroll
    for (int m = 0; m < 8; ++m) {
        int s = m * 512 + tid;
        f32x4 e = *((const f32x4*)tb + s);
        st[s] = e.x;
        enc_r[m] = (e.w == segPar) ? (useH ? e.y : e.z) : -1.0f;
    }
    __syncthreads();

    // 2. dec from st, alphas + group G from st; write pk (separate region)
#pragma unroll
    for (int m = 0; m < 8; ++m) {
        int s = m * 512 + tid;
        float dec = (s == NS - 1) ? 0.0f
                   : __expf(-(st[s + 1] - st[s]) * INV_TEMP);
        f32x2 v; v.x = dec; v.y = enc_r[m];
        pk[s] = v;
    }
    float alp[P2_GC];
    {
        const int gs = g * P2_GS;
#pragma unroll
        for (int q = 0; q < P2_GC; ++q) {
            int se = gs + q * CL;
            alp[q] = (g == P2_NG - 1 && q == P2_GC - 1) ? 0.0f
                     : __expf(-(st[se + CL] - st[se]) * INV_TEMP);
        }
        if (ci == 0) {
            shG[g] = (g == P2_NG - 1) ? 0.0f
                     : __expf(-(st[gs + P2_GS] - st[gs]) * INV_TEMP);
        }
    }
    __syncthreads();

    // 3. per-chunk local suffix sums (zero carry), 8 chunks in registers
    float cs[P2_GC];
    {
        const int gs = g * P2_GS;
#pragma unroll
        for (int q = P2_GC - 1; q >= 0; --q) {
            float v = 0.0f;
            const int base = gs + q * CL;
#pragma unroll
            for (int i = CL - 1; i >= 0; --i) {
                f32x2 e = pk[base + i];
                v = fmaf(v, e.x, (e.y == crel) ? 1.0f : 0.0f);
            }
            cs[q] = v;
        }
    }

    // 4. group-local combine -> L (value at group start, zero incoming)
    float L = 0.0f;
#pragma unroll
    for (int q = P2_GC - 1; q >= 0; --q) L = fmaf(alp[q], L, cs[q]);
    shL[g][ci] = L;
    __syncthreads();

    // 5. carry into group g = suffix over groups j > g
    float X = 0.0f;
#pragma unroll
    for (int j = P2_NG - 1; j >= 1; --j)
        if (j > g) X = fmaf(shG[j], X, shL[j][ci]);

    // 6. chunk-level replay with carry, store rstart[b, g*8+q, c]
    float* rs = rstart + ((size_t)b * NCH + g * P2_GC) * NC
                + (ctile * 16 + ci);
    float carry = X;
#pragma unroll
    for (int q = P2_GC - 1; q >= 0; --q) {
        carry = fmaf(alp[q], carry, cs[q]);
        rs[(size_t)q * NC] = carry;
    }
}

// ---------------------------------------------------------------------------
// Phase 2: fused scan + soft-CE loss.  (R16 verbatim — best config 31.0 µs.)
// ---------------------------------------------------------------------------
__global__ __launch_bounds__(256) void tdl_loss_kernel(
    const float* __restrict__ pred, const float* __restrict__ target,
    const float* __restrict__ rstart, float* __restrict__ partials)
{
    const int blk = blockIdx.x;
    const int b = blk >> 8;              // / NCH
    const int k = blk & (NCH - 1);
    const int s0 = k * CL;
    const int tid = threadIdx.x;
    const int wv  = (tid >> 6) & 1;      // 0: H-pair, 1: W-pair
    const int rh  = tid >> 7;            // 0: rows 15..8, 1: rows 7..0
    const int ln  = tid & 63;

    __shared__ f32x4 ev[CL];             // {dec, p, h, w}
    __shared__ float sh4[4];

    if (tid < CL) {
        const float* tg = target + ((size_t)b * NS + s0 + tid) * 4;
        float t0 = tg[0];
        int s = s0 + tid;
        float dec = (s == NS - 1 || s == 0) ? 0.0f
                   : __expf(-(tg[4] - t0) * INV_TEMP);   // tg[4] = t[s+1]
        f32x4 e; e.x = dec; e.y = tg[3]; e.z = tg[1]; e.w = tg[2];
        ev[tid] = e;
    }
    __syncthreads();

    const int lc   = ln * 4;             // lane offset within a 256-ch quarter
    const int segA = wv * 2;             // even segment of my pair
    const size_t pbase = (size_t)b * NS * NC;

    float vA[8], vB[8];
    if (k == NCH - 1) {
#pragma unroll
        for (int j = 0; j < 8; ++j) { vA[j] = 0.0f; vB[j] = 0.0f; }
    } else {
        const float* rrow = rstart + ((size_t)b * NCH + k + 1) * NC;
#pragma unroll
        for (int q = 0; q < 2; ++q) {
            f32x4 ra = *(const f32x4*)(rrow + segA * 512 + q * 256 + lc);
            f32x4 rb = *(const f32x4*)(rrow + (segA + 1) * 512 + q * 256 + lc);
#pragma unroll
            for (int j = 0; j < 4; ++j) {
                vA[q*4+j] = ra[j] * LOG2E;
                vB[q*4+j] = rb[j] * LOG2E;
            }
        }
    }

    if (rh) {
#pragma unroll
        for (int i = CL - 1; i >= CL / 2; --i) {
            f32x4 e = ev[i];
            const float d    = e.x;
            const float pv   = e.y;
            const float idxf = wv ? e.w : e.z;
            const float aA = (1.0f - pv) * LOG2E;
            const float aB = pv * LOG2E;
#pragma unroll
            for (int q = 0; q < 2; ++q) {
#pragma unroll
                for (int j = 0; j < 4; ++j) {
                    const int id = q * 4 + j;
                    const float myc = (float)(q * 256 + lc + j);
                    const bool m = (idxf == myc);
                    vA[id] = fmaf(vA[id], d, m ? aA : 0.0f);
                    vB[id] = fmaf(vB[id], d, m ? aB : 0.0f);
                }
            }
        }
    }

    const int itop = rh ? (CL / 2 - 1) : (CL - 1);  // 7 or 15

    f32x4 pf0[2], pf1[2];
    {
        const int paT = (int)ev[itop].y;
        const float* pr = pred + pbase + (size_t)(s0 + itop) * NC
                          + (segA + paT) * 512 + lc;
        pf0[0] = *(const f32x4*)pr; pf0[1] = *(const f32x4*)(pr + 256);
        const int paU = (int)ev[itop - 1].y;
        const float* pr2 = pred + pbase + (size_t)(s0 + itop - 1) * NC
                           + (segA + paU) * 512 + lc;
        pf1[0] = *(const f32x4*)pr2; pf1[1] = *(const f32x4*)(pr2 + 256);
    }

    float acc = 0.0f;
#pragma unroll
    for (int r = 0; r < 8; ++r) {
        const int i = itop - r;
        f32x4 cur0 = pf0[0], cur1 = pf0[1];
        pf0[0] = pf1[0]; pf0[1] = pf1[1];
        if (r < 6) {
            const int pa = (int)ev[i - 2].y;
            const float* pr = pred + pbase + (size_t)(s0 + i - 2) * NC
                              + (segA + pa) * 512 + lc;
            pf1[0] = *(const f32x4*)pr; pf1[1] = *(const f32x4*)(pr + 256);
        }

        f32x4 e = ev[i];
        const float d    = e.x;
        const float pv   = e.y;                    // 0.0 or 1.0 exactly
        const float idxf = wv ? e.w : e.z;
        const float aA = (1.0f - pv) * LOG2E;
        const float aB = pv * LOG2E;

        float ser = 0.0f, dot = 0.0f, sep = 0.0f;
#pragma unroll
        for (int q = 0; q < 2; ++q) {
            const f32x4 cq = q ? cur1 : cur0;
#pragma unroll
            for (int j = 0; j < 4; ++j) {
                const int id = q * 4 + j;
                const float myc = (float)(q * 256 + lc + j);
                const bool m = (idxf == myc);
                vA[id] = fmaf(vA[id], d, m ? aA : 0.0f);
                vB[id] = fmaf(vB[id], d, m ? aB : 0.0f);
                const float vs = (pv != 0.0f) ? vB[id] : vA[id];
                const float ex = exp2f(vs);
                const float pj = cq[j];
                ser += ex;
                dot = fmaf(ex, pj, dot);
                sep += __expf(pj);
            }
        }

        WAVE_SUM_DPP(ser)
        WAVE_SUM_DPP(dot)
        WAVE_SUM_DPP(sep)
        const float serT = wave_total(ser);
        const float dotT = wave_total(dot);
        const float sepT = wave_total(sep);
        acc += __logf(sepT) - dotT * __builtin_amdgcn_rcpf(serT);
    }

    if (ln == 0) sh4[tid >> 6] = acc;
    __syncthreads();
    if (tid == 0) partials[blk] = sh4[0] + sh4[1] + sh4[2] + sh4[3];
}

// ---------------------------------------------------------------------------
// Phase 3: tiny reduce — 1 block, 256 threads, 4 KB of partials -> out[0].
// ---------------------------------------------------------------------------
__global__ __launch_bounds__(256) void tdl_reduce_kernel(
    const float* __restrict__ partials, float* __restrict__ out)
{
    const int tid = threadIdx.x;
    __shared__ float sh4[4];

    float s = 0.0f;
#pragma unroll
    for (int i = 0; i < LOSS_NBLK / 256; ++i)
        s += partials[i * 256 + tid];
#pragma unroll
    for (int off = 32; off > 0; off >>= 1)
        s += __shfl_xor(s, off, 64);
    if ((tid & 63) == 0) sh4[tid >> 6] = s;
    __syncthreads();
    if (tid == 0)
        out[0] = (sh4[0] + sh4[1] + sh4[2] + sh4[3])
                 * (1.0f / ((float)NB * (float)NS));
}

// ---------------------------------------------------------------------------
extern "C" void kernel_launch(void* const* d_in, const int* in_sizes, int n_in,
                              void* d_out, int out_size, void* d_ws, size_t ws_size,
                              hipStream_t stream)
{
    const float* pred   = (const float*)d_in[0];
    const float* target = (const float*)d_in[1];
    float* out    = (float*)d_out;
    float* rstart = (float*)d_ws;                       // 8 MiB
    float* partials = rstart + (size_t)NB * NCH * NC;   // 4 KiB

    tdl_scan_kernel<<<NB * 128, 512, 0, stream>>>(target, rstart);
    tdl_loss_kernel<<<NB * NCH, 256, 0, stream>>>(pred, target, rstart, partials);
    tdl_reduce_kernel<<<1, 256, 0, stream>>>(partials, out);
}